// Round 1
// baseline (207.920 us; speedup 1.0000x reference)
//
#include <hip/hip_runtime.h>
#include <math.h>

// Problem constants
#define BATCH 256
#define IC    1152
#define EDIM  8
#define NC    10
#define DV    16

// Tiling
#define ITILE  8                    // i's covered by thread layout (il = 0..7)
#define NCHUNK 4                    // i-chunks looped per block
#define ITOT   (ITILE * NCHUNK)     // 32 i's per block
#define NB     4                    // b's per block
#define NTHREADS 256
#define NSLAB  (IC / ITOT)          // 36
#define BCHUNKS (BATCH / NB)        // 64
#define SCD (NC * DV)               // 160
#define SFLOATS (BATCH * SCD)       // 40960 floats per s-accumulator buffer

// ---------------------------------------------------------------------------
// DPP-based 16-lane (row) sum reduce — all VALU, no DS pipe. HW-verified.
// ---------------------------------------------------------------------------
template<int CTRL>
__device__ __forceinline__ float dpp_add(float x) {
    int r = __builtin_amdgcn_update_dpp(0, __float_as_int(x), CTRL, 0xF, 0xF, true);
    return x + __int_as_float(r);
}
__device__ __forceinline__ float row_reduce16(float x) {
    x = dpp_add<0xB1>(x);   // quad_perm [1,0,3,2] : xor 1
    x = dpp_add<0x4E>(x);   // quad_perm [2,3,0,1] : xor 2
    x = dpp_add<0x141>(x);  // row_half_mirror     : xor 4
    x = dpp_add<0x140>(x);  // row_mirror          : xor 8
    return x;
}

// ---------------------------------------------------------------------------
// Cross-half (lane ^ 32) sum. gfx950: v_permlane32_swap — pure VALU, no
// DS pipe / lgkmcnt wait. ret.x = low half broadcast, ret.y = high half
// broadcast; per-lane ret.x+ret.y == x + partner(x).
// ---------------------------------------------------------------------------
#if __has_builtin(__builtin_amdgcn_permlane32_swap)
typedef int int2v __attribute__((ext_vector_type(2)));
__device__ __forceinline__ float cross32_sum(float x) {
    int2v r = __builtin_amdgcn_permlane32_swap(__float_as_int(x), __float_as_int(x),
                                               false, false);
    return __int_as_float(r[0]) + __int_as_float(r[1]);
}
#else
__device__ __forceinline__ float cross32_sum(float x) { return x + __shfl_xor(x, 32); }
#endif

// ---------------------------------------------------------------------------
// Main fused kernel. LANE MAP (changed this round): d = bits0-3,
// il_lo = bit4, ch = bit5 (so the softmax cross-ch sum is lane^32 =
// permlane32_swap, VALU), il_hi = bits6-7.
//
// s accumulation: fp32 atomicAdd into a dense [256][160] buffer (144
// adds/cell total — negligible contention). The squash of the PREVIOUS
// iteration's s is fused into this kernel's prologue; v lives in 20
// registers per thread (no per-body global v loads).
//
// SPILL HISTORY (do not regress): keep __launch_bounds__(256,2) — cap 256
// VGPR. Live regs now ~95 (sacc 20 + vreg 20 + W frag 40 + misc).
//
// Softmax: max-pass removed (|logits| <= ~6 << 88, exp cannot overflow);
// 1/sum via v_rcp_f32 (rel err ~1e-7, irrelevant vs 2e-3 tolerance).
//
// MODE 1: c = softmax(bias)                      -> atomics into s_out; also
//         zeroes z0,z1 (the next two s buffers) from icb==0/1 blocks.
// MODE 2: squash(s_in)->v (prologue), b2 = (u.v1) + 2*bias stored, softmax
// MODE 3: b3 = (u.v2) + b2 + bias, softmax
// ---------------------------------------------------------------------------
template<int MODE>
__global__ __launch_bounds__(NTHREADS, 2)
void caps_main(const float* __restrict__ x,
               const float* __restrict__ W,
               const float* __restrict__ bias,
               const float* __restrict__ s_in,
               float* __restrict__ b2,
               float* __restrict__ s_out,
               float* __restrict__ z0,
               float* __restrict__ z1)
{
    __shared__ float sx[NB][ITOT * EDIM];   // 4 KB
    __shared__ float vls[NB][SCD];          // 2.5 KB (used MODE>=2)

    const int tid = threadIdx.x;
    const int d   = tid & 15;
    const int ch  = (tid >> 5) & 1;                       // lane bit 5
    const int il  = ((tid >> 4) & 1) | ((tid >> 6) << 1); // bit4 + 2*bits6-7
    const int icb = blockIdx.x;              // 0..35
    const int bcb = blockIdx.y;              // 0..63
    const int i0  = icb * ITOT;
    const int b0  = bcb * NB;

    // ---- stage x slice: 256 float4, one per thread, coalesced ----
    {
        const float4* xg = (const float4*)x;
        float4* xs = (float4*)&sx[0][0];
        int bb = tid >> 6;
        int w  = tid & 63;
        xs[tid] = xg[(size_t)(b0 + bb) * (IC * EDIM / 4) + i0 * (EDIM / 4) + w];
    }

    if (MODE == 1) {
        // zero the next two s-accumulator buffers (ordering via stream)
        if (icb < 2) {
            float* z = (icb == 0) ? z0 : z1;
            #pragma unroll
            for (int t = 0; t < 3; ++t) {
                int j = t * NTHREADS + tid;
                if (j < NB * SCD) z[(size_t)b0 * SCD + j] = 0.f;
            }
        }
    } else {
        // fused squash: v = squash(s_in) for this block's 4 b's.
        // j is contiguous in [b][c][d] so each DPP row of 16 lanes holds
        // d=0..15 of one (b,c).
        #pragma unroll
        for (int t = 0; t < 3; ++t) {
            int j = t * NTHREADS + tid;
            if (j < NB * SCD) {
                float s  = s_in[(size_t)b0 * SCD + j];
                float sq = row_reduce16(s * s);
                float scale = sq / ((1.0f + sq) * sqrtf(sq + 1e-7f));
                (&vls[0][0])[j] = scale * s;
            }
        }
    }

    float sacc[NB][5];
    #pragma unroll
    for (int bb = 0; bb < NB; ++bb)
        #pragma unroll
        for (int k = 0; k < 5; ++k) sacc[bb][k] = 0.f;

    __syncthreads();

    // v into registers: 20 ds_reads once per block (replaces 80 global
    // loads per thread in the old per-body path)
    float vreg[NB][5];
    if (MODE != 1) {
        #pragma unroll
        for (int bb = 0; bb < NB; ++bb)
            #pragma unroll
            for (int k = 0; k < 5; ++k)
                vreg[bb][k] = vls[bb][(ch * 5 + k) * 16 + d];
    }

    const float4* Wg = (const float4*)W;

    #pragma unroll 1
    for (int ic = 0; ic < NCHUNK; ++ic) {
        const int i = i0 + ic * ITILE + il;

        // W fragment + bias for this i-chunk
        float4 w4[5][2];
        float  bv[5];
        #pragma unroll
        for (int k = 0; k < 5; ++k) {
            int c = ch * 5 + k;
            size_t base = ((size_t)(i * NC + c) * DV + d) * 2;
            w4[k][0] = Wg[base];
            w4[k][1] = Wg[base + 1];
            bv[k]    = bias[i * NC + c];
        }

        float cw[5];
        if (MODE == 1) {
            // softmax(bias[i,:]) — batch-independent, once per i-chunk
            float ssum = 0.f, ex[5];
            #pragma unroll
            for (int k = 0; k < 5; ++k) { ex[k] = __expf(bv[k]); ssum += ex[k]; }
            ssum = cross32_sum(ssum);
            float inv = __builtin_amdgcn_rcpf(ssum);
            #pragma unroll
            for (int k = 0; k < 5; ++k) cw[k] = ex[k] * inv;
        }

        #pragma unroll
        for (int bb = 0; bb < NB; ++bb) {
            const float4 x0 = ((const float4*)&sx[bb][(ic * ITILE + il) * EDIM])[0];
            const float4 x1 = ((const float4*)&sx[bb][(ic * ITILE + il) * EDIM])[1];

            // u_hat[b, i, c_k, d]
            float u[5];
            #pragma unroll
            for (int k = 0; k < 5; ++k) {
                float acc = w4[k][0].x * x0.x;
                acc = fmaf(w4[k][0].y, x0.y, acc);
                acc = fmaf(w4[k][0].z, x0.z, acc);
                acc = fmaf(w4[k][0].w, x0.w, acc);
                acc = fmaf(w4[k][1].x, x1.x, acc);
                acc = fmaf(w4[k][1].y, x1.y, acc);
                acc = fmaf(w4[k][1].z, x1.z, acc);
                acc = fmaf(w4[k][1].w, x1.w, acc);
                u[k] = acc;
            }

            if (MODE != 1) {
                // agreement: sum over d via DPP row reduce (VALU only)
                float t[5];
                #pragma unroll
                for (int k = 0; k < 5; ++k) t[k] = u[k] * vreg[bb][k];
                #pragma unroll
                for (int k = 0; k < 5; ++k) t[k] = row_reduce16(t[k]);

                float br[5];
                float* bp = b2 + (((size_t)(b0 + bb) * IC + i) * 2 + ch) * 8;  // padded
                if (MODE == 2) {
                    #pragma unroll
                    for (int k = 0; k < 5; ++k) br[k] = fmaf(2.0f, bv[k], t[k]);
                    if (d == 0) {
                        #pragma unroll
                        for (int k = 0; k < 5; ++k) bp[k] = br[k];
                    }
                } else {
                    #pragma unroll
                    for (int k = 0; k < 5; ++k) br[k] = t[k] + bp[k] + bv[k];
                }
                // softmax over 10 c's: 5 local + partner half via permlane32
                // (no max-pass: logits bounded far below exp overflow)
                float ssum = 0.f, ex[5];
                #pragma unroll
                for (int k = 0; k < 5; ++k) { ex[k] = __expf(br[k]); ssum += ex[k]; }
                ssum = cross32_sum(ssum);
                float inv = __builtin_amdgcn_rcpf(ssum);
                #pragma unroll
                for (int k = 0; k < 5; ++k) cw[k] = ex[k] * inv;
            }

            // register s-accumulation — no LDS, no shuffle, no barrier
            #pragma unroll
            for (int k = 0; k < 5; ++k)
                sacc[bb][k] = fmaf(cw[k], u[k], sacc[bb][k]);
        }
    }

    // ---- epilogue: combine il-pairs (lane^16), one atomic per wave/cell ----
    #pragma unroll
    for (int bb = 0; bb < NB; ++bb) {
        #pragma unroll
        for (int k = 0; k < 5; ++k) {
            float s = sacc[bb][k] + __shfl_xor(sacc[bb][k], 16);
            if ((tid & 16) == 0)
                atomicAdd(&s_out[(size_t)(b0 + bb) * SCD + (ch * 5 + k) * 16 + d], s);
        }
    }
}

// ---------------------------------------------------------------------------
// Final squash only (inter-iteration squashes are fused into caps_main
// prologues). 40960 values, one per thread; rows of 16 lanes = d 0..15.
// ---------------------------------------------------------------------------
__global__ __launch_bounds__(256)
void caps_squash(const float* __restrict__ s_sum, float* __restrict__ out)
{
    const int idx = blockIdx.x * 256 + threadIdx.x;
    float s  = s_sum[idx];
    float sq = row_reduce16(s * s);
    float scale = sq / ((1.0f + sq) * sqrtf(sq + 1e-7f));
    out[idx] = scale * s;
}

// ---------------------------------------------------------------------------
extern "C" void kernel_launch(void* const* d_in, const int* in_sizes, int n_in,
                              void* d_out, int out_size, void* d_ws, size_t ws_size,
                              hipStream_t stream)
{
    const float* x    = (const float*)d_in[0];   // [256,1152,8]
    const float* W    = (const float*)d_in[1];   // [1152,10,16,8]
    const float* bias = (const float*)d_in[2];   // [1152,10]
    float* out = (float*)d_out;                  // [256,10,16]

    float* sA = (float*)d_ws;        // 40960 f   (s1 accumulator)
    float* sB = sA + SFLOATS;        // 40960 f   (s2 accumulator)
    float* sC = sB + SFLOATS;        // 40960 f   (s3 accumulator)
    float* b2 = sC + SFLOATS;        // padded [b][i][2][8] = 4,718,592 f
    // total ws use: ~18.5 MB (was ~25 MB)

    dim3 grid(NSLAB, BCHUNKS);       // 36 x 64 = 2304 blocks

    hipMemsetAsync(sA, 0, SFLOATS * sizeof(float), stream);
    // iter 1 (zeroes sB, sC for the later atomics)
    caps_main<1><<<grid, NTHREADS, 0, stream>>>(x, W, bias, nullptr, b2, sA, sB, sC);
    // iter 2 (fused squash of sA -> v in prologue)
    caps_main<2><<<grid, NTHREADS, 0, stream>>>(x, W, bias, sA, b2, sB, nullptr, nullptr);
    // final routing pass (fused squash of sB -> v)
    caps_main<3><<<grid, NTHREADS, 0, stream>>>(x, W, bias, sB, b2, sC, nullptr, nullptr);
    caps_squash<<<160, 256, 0, stream>>>(sC, out);
}

// Round 3
// 169.647 us; speedup vs baseline: 1.2256x; 1.2256x over previous
//
#include <hip/hip_runtime.h>
#include <math.h>

// Problem constants
#define BATCH 256
#define IC    1152
#define EDIM  8
#define NC    10
#define DV    16

// Tiling
#define ITILE  8                    // i's covered by thread layout (il = 0..7)
#define NCHUNK 4                    // i-chunks looped per block
#define ITOT   (ITILE * NCHUNK)     // 32 i's per block
#define NB     4                    // b's per block (register s-acc = 20 VGPRs)
#define NTHREADS 256                // 256 = 16 d * 2 il_lo * 2 ch * 4 il_hi
#define NWAVES 4
#define NSLAB  (IC / ITOT)          // 36 partial slabs
#define BCHUNKS (BATCH / NB)        // 64
#define SCD (NC * DV)               // 160
#define SPART_STRIDE (BATCH * SCD)  // 40960 floats per slab
#define L2E 1.4426950408889634f

// ---------------------------------------------------------------------------
// DPP-based 16-lane (row) sum reduce — all VALU, no DS pipe.
// MUST stay on __builtin_amdgcn_update_dpp: the compiler inserts the
// mandatory VALU->DPP hazard wait-states. R2's hand-written v_add_f32_dpp
// inline asm skipped them (hazard recognizer doesn't scan asm bodies) and
// silently read stale lanes -> absmax 0.39 FAIL. Do not regress.
// ---------------------------------------------------------------------------
template<int CTRL>
__device__ __forceinline__ float dpp_add(float x) {
    int r = __builtin_amdgcn_update_dpp(0, __float_as_int(x), CTRL, 0xF, 0xF, true);
    return x + __int_as_float(r);
}
__device__ __forceinline__ float row_reduce16(float x) {
    x = dpp_add<0xB1>(x);   // quad_perm [1,0,3,2] : xor 1
    x = dpp_add<0x4E>(x);   // quad_perm [2,3,0,1] : xor 2
    x = dpp_add<0x141>(x);  // row_half_mirror     : xor 4
    x = dpp_add<0x140>(x);  // row_mirror          : xor 8
    return x;
}

// ---------------------------------------------------------------------------
// Cross-half (lane ^ 32) sum, pure VALU on gfx950 (no DS pipe / lgkmcnt).
// r[0]+r[1] == x + partner(x) in every lane. Builtin — HW-verified in R1.
// ---------------------------------------------------------------------------
typedef int int2v __attribute__((ext_vector_type(2)));
#if __has_builtin(__builtin_amdgcn_permlane32_swap)
__device__ __forceinline__ float cross32_sum(float x) {
    int2v r = __builtin_amdgcn_permlane32_swap(__float_as_int(x), __float_as_int(x),
                                               false, false);
    return __int_as_float(r[0]) + __int_as_float(r[1]);
}
#else
__device__ __forceinline__ float cross32_sum(float x) { return x + __shfl_xor(x, 32); }
#endif

#if __has_builtin(__builtin_amdgcn_exp2f)
#define EXP2F(x) __builtin_amdgcn_exp2f(x)
#else
#define EXP2F(x) exp2f(x)
#endif

// ---------------------------------------------------------------------------
// Main fused kernel. LANE MAP: d = bits0-3, il_lo = bit4, ch = bit5,
// il_hi = bits6-7 (== wid). ch at bit5 makes the softmax cross-ch sum a
// v_permlane32_swap (VALU).
//
// STRUCTURE = R0's proven one: slab s-partials written by the epilogue
// (plain stores), reduced+squashed by a separate tiny kernel. R1's
// device-atomic s-accumulation quadrupled HBM writes (per-XCD L2s are not
// coherent; device atomics go to fabric) and stays reverted.
//
// v HANDLING (R3): staged once per block into LDS (2.5 KB, coalesced,
// piggybacks on the existing barrier); per-body reads are broadcast /
// conflict-free ds_reads. This is R1's latency win WITHOUT the vreg[4][5]
// hoist (+20 VGPR -> occupancy 26.6%->18.0%) that caused the R1 slowdown.
//
// SPILL HISTORY (do not regress):
//   (256,4)/(256,3) caps spilled; (256,2) cap 256 with NB=4 allocates ~68
//   VGPR, no spill, and occupancy ~26%. Keep per-body v out of registers.
//
// NUMERICS: softmax max-pass removed (|logits| <~ 20 << 88 so exp cannot
// overflow; verified passing in R1). 1/sum via v_rcp_f32 (rel err ~1e-7).
// Routing logits kept in log2 domain: v_in arrives pre-scaled by log2(e)
// (caps_squash writes it), bias is scaled once per i-chunk, so softmax
// exp is a raw v_exp_f32 (exp2) with no per-element multiply. b2 stores
// scaled logits (internal-only buffer, consistent between MODE 2 and 3).
//
// MODE 1: c = softmax(bias)                             -> s1 partials
// MODE 2: b2 = L2E*(u.v1) + 2*L2E*bias (stored), softmax -> s2 partials
// MODE 3: b3 = L2E*(u.v2) + b2 + L2E*bias, softmax       -> s3 partials
// ---------------------------------------------------------------------------
template<int MODE>
__global__ __launch_bounds__(NTHREADS, 2)
void caps_main(const float* __restrict__ x,
               const float* __restrict__ W,
               const float* __restrict__ bias,
               const float* __restrict__ v_in,   // pre-scaled by L2E
               float* __restrict__ b2,
               float* __restrict__ s_part)
{
    __shared__ float sx[NB][ITOT * EDIM];    // 4 KB
    __shared__ float swv[NWAVES][NB][SCD];   // 10 KB — wave-private slabs
    __shared__ float vls[NB][SCD];           // 2.5 KB — v tile (MODE != 1)

    const int tid = threadIdx.x;
    const int d   = tid & 15;
    const int ch  = (tid >> 5) & 1;                       // lane bit 5
    const int il  = ((tid >> 4) & 1) | (((tid >> 6) & 3) << 1);
    const int wid = tid >> 6;                // 0..3
    const int icb = blockIdx.x;              // 0..35
    const int bcb = blockIdx.y;              // 0..63
    const int i0  = icb * ITOT;
    const int b0  = bcb * NB;

    // ---- stage x slice: 256 float4, one per thread, coalesced ----
    {
        const float4* xg = (const float4*)x;
        float4* xs = (float4*)&sx[0][0];
        int bb = tid >> 6;                   // 64 float4 per b row
        int w  = tid & 63;
        xs[tid] = xg[(size_t)(b0 + bb) * (IC * EDIM / 4) + i0 * (EDIM / 4) + w];
    }
    // ---- stage v tile (640 floats, coalesced) ----
    if (MODE != 1) {
        #pragma unroll
        for (int t = 0; t < 3; ++t) {
            int j = t * NTHREADS + tid;
            if (j < NB * SCD)
                (&vls[0][0])[j] = v_in[(size_t)b0 * SCD + j];
        }
    }

    float sacc[NB][5];
    #pragma unroll
    for (int bb = 0; bb < NB; ++bb)
        #pragma unroll
        for (int k = 0; k < 5; ++k) sacc[bb][k] = 0.f;

    __syncthreads();

    const float4* Wg = (const float4*)W;

    #pragma unroll 1
    for (int ic = 0; ic < NCHUNK; ++ic) {
        const int i = i0 + ic * ITILE + il;

        // W fragment + bias for this i-chunk
        float4 w4[5][2];
        float  bv[5];
        #pragma unroll
        for (int k = 0; k < 5; ++k) {
            int c = ch * 5 + k;
            size_t base = ((size_t)(i * NC + c) * DV + d) * 2;
            w4[k][0] = Wg[base];
            w4[k][1] = Wg[base + 1];
            bv[k]    = bias[i * NC + c];
        }

        float cw[5];
        float bvs[5];
        if (MODE == 1) {
            // softmax(bias[i,:]) — batch-independent, once per i-chunk
            float ssum = 0.f, ex[5];
            #pragma unroll
            for (int k = 0; k < 5; ++k) { ex[k] = __expf(bv[k]); ssum += ex[k]; }
            ssum = cross32_sum(ssum);
            float inv = __builtin_amdgcn_rcpf(ssum);
            #pragma unroll
            for (int k = 0; k < 5; ++k) cw[k] = ex[k] * inv;
        } else {
            #pragma unroll
            for (int k = 0; k < 5; ++k) bvs[k] = bv[k] * L2E;
        }

        #pragma unroll
        for (int bb = 0; bb < NB; ++bb) {
            const int b = b0 + bb;
            const float4 x0 = ((const float4*)&sx[bb][(ic * ITILE + il) * EDIM])[0];
            const float4 x1 = ((const float4*)&sx[bb][(ic * ITILE + il) * EDIM])[1];

            // u_hat[b, i, c_k, d]
            float u[5];
            #pragma unroll
            for (int k = 0; k < 5; ++k) {
                float acc = w4[k][0].x * x0.x;
                acc = fmaf(w4[k][0].y, x0.y, acc);
                acc = fmaf(w4[k][0].z, x0.z, acc);
                acc = fmaf(w4[k][0].w, x0.w, acc);
                acc = fmaf(w4[k][1].x, x1.x, acc);
                acc = fmaf(w4[k][1].y, x1.y, acc);
                acc = fmaf(w4[k][1].z, x1.z, acc);
                acc = fmaf(w4[k][1].w, x1.w, acc);
                u[k] = acc;
            }

            if (MODE != 1) {
                // agreement (L2E-scaled via v): sum over d via DPP row reduce
                const float* vb = &vls[bb][ch * 80 + d];
                float t[5];
                #pragma unroll
                for (int k = 0; k < 5; ++k) t[k] = u[k] * vb[k * 16];
                #pragma unroll
                for (int k = 0; k < 5; ++k) t[k] = row_reduce16(t[k]);

                float br[5];
                float* bp = b2 + (((size_t)b * IC + i) * 2 + ch) * 8;  // padded
                if (MODE == 2) {
                    #pragma unroll
                    for (int k = 0; k < 5; ++k) br[k] = fmaf(2.0f, bvs[k], t[k]);
                    if (d == 0) {
                        #pragma unroll
                        for (int k = 0; k < 5; ++k) bp[k] = br[k];
                    }
                } else {
                    #pragma unroll
                    for (int k = 0; k < 5; ++k) br[k] = t[k] + bp[k] + bvs[k];
                }
                // softmax over 10 c's: 5 local + partner half via permlane32.
                // Logits are log2-domain -> raw v_exp_f32, no max-pass.
                float ssum = 0.f, ex[5];
                #pragma unroll
                for (int k = 0; k < 5; ++k) { ex[k] = EXP2F(br[k]); ssum += ex[k]; }
                ssum = cross32_sum(ssum);
                float inv = __builtin_amdgcn_rcpf(ssum);
                #pragma unroll
                for (int k = 0; k < 5; ++k) cw[k] = ex[k] * inv;
            }

            // register s-accumulation — no LDS, no shuffle, no barrier
            #pragma unroll
            for (int k = 0; k < 5; ++k)
                sacc[bb][k] = fmaf(cw[k], u[k], sacc[bb][k]);
        }
    }

    // ---- epilogue: il-pair reduce + wave slabs + 4-way reduce + flush ----
    #pragma unroll
    for (int bb = 0; bb < NB; ++bb) {
        #pragma unroll
        for (int k = 0; k < 5; ++k) {
            float s = sacc[bb][k] + __shfl_xor(sacc[bb][k], 16);
            if ((tid & 16) == 0)
                swv[wid][bb][ch * 80 + k * 16 + d] = s;
        }
    }
    __syncthreads();
    for (int j = tid; j < NB * SCD; j += NTHREADS) {    // 640 elems
        int bb = j / SCD;
        int cd = j - bb * SCD;
        float s = (swv[0][bb][cd] + swv[1][bb][cd])
                + (swv[2][bb][cd] + swv[3][bb][cd]);
        s_part[((size_t)icb * BATCH + b0 + bb) * SCD + cd] = s;
    }
}

// ---------------------------------------------------------------------------
// Reduce s-partials over the 36 slabs and apply squash.
// Block = 16 (b,c) groups x 16 d. Grid = 2560/16 = 160 blocks.
// mult = L2E for intermediate v (log2-domain routing), 1.0 for final out.
// ---------------------------------------------------------------------------
__global__ __launch_bounds__(256)
void caps_squash(const float* __restrict__ s_part, float* __restrict__ out,
                 float mult)
{
    const int tid = threadIdx.x;
    const int bc  = blockIdx.x * 16 + (tid >> 4);
    const size_t off = (size_t)bc * DV + (tid & 15);

    float a[4] = {0.f, 0.f, 0.f, 0.f};
    #pragma unroll
    for (int ic = 0; ic < NSLAB; ic += 4) {
        #pragma unroll
        for (int j = 0; j < 4; ++j)
            a[j] += s_part[(size_t)(ic + j) * SPART_STRIDE + off];
    }
    float s = (a[0] + a[1]) + (a[2] + a[3]);

    float sq = row_reduce16(s * s);

    // scale = sq/(1+sq)/sqrt(sq+EPS), EPS = 1e-7 (matches reference)
    float scale = sq / ((1.0f + sq) * sqrtf(sq + 1e-7f));
    out[off] = (mult * scale) * s;
}

// ---------------------------------------------------------------------------
extern "C" void kernel_launch(void* const* d_in, const int* in_sizes, int n_in,
                              void* d_out, int out_size, void* d_ws, size_t ws_size,
                              hipStream_t stream)
{
    const float* x    = (const float*)d_in[0];   // [256,1152,8]
    const float* W    = (const float*)d_in[1];   // [1152,10,16,8]
    const float* bias = (const float*)d_in[2];   // [1152,10]
    float* out = (float*)d_out;                  // [256,10,16]

    float* ws     = (float*)d_ws;
    float* s_part = ws;                                       // 36*40960 = 1,474,560 f
    float* v      = s_part + (size_t)NSLAB * SPART_STRIDE;    // 40,960 f (L2E-scaled)
    float* b2     = v + SPART_STRIDE;                         // padded: 4,718,592 f
    // total ws use: ~25 MB

    dim3 grid(NSLAB, BCHUNKS);   // 36 x 64 = 2304 blocks

    // iter 1
    caps_main<1><<<grid, NTHREADS, 0, stream>>>(x, W, bias, v, b2, s_part);
    caps_squash<<<160, 256, 0, stream>>>(s_part, v, L2E);
    // iter 2
    caps_main<2><<<grid, NTHREADS, 0, stream>>>(x, W, bias, v, b2, s_part);
    caps_squash<<<160, 256, 0, stream>>>(s_part, v, L2E);
    // final
    caps_main<3><<<grid, NTHREADS, 0, stream>>>(x, W, bias, v, b2, s_part);
    caps_squash<<<160, 256, 0, stream>>>(s_part, out, 1.0f);
}